// Round 1
// baseline (3118.645 us; speedup 1.0000x reference)
//
#include <hip/hip_runtime.h>

// Problem constants: x(64,512,64,64) fp32; meta(32,512); Wq(512,512); bq(512)
// b=64, c=d=512, hw=4096, n=32, M=b*n=2048, 3 slot-attention iterations.

#define F4(p)  (*reinterpret_cast<float4*>(p))
#define CF4(p) (*reinterpret_cast<const float4*>(p))

// stats buffer float offsets
#define O_SUM1 0
#define O_SQ1  512
#define O_SUM2 1024
#define O_SQ2  1056
#define O_SC1  1088
#define O_SH1  1600
#define O_SC2  2112
#define O_SH2  2144
#define O_RS   2176   // rowsum[2048]

// ---------------- init / blend ----------------
// slots[m, d] = meta[m%32, d]; 2048x512 floats = 262144 float4
__global__ void k_init_slots(const float* __restrict__ meta, float* __restrict__ slots) {
    int f = blockIdx.x * 256 + threadIdx.x;      // float4 index
    int m = f >> 7;                               // 128 float4 per row
    int d4 = f & 127;
    F4(slots + (size_t)f * 4) = CF4(meta + ((size_t)((m & 31) << 7) + d4) * 4);
}

// slots = 0.9*slots + 0.1*new_slots
__global__ void k_blend(float* __restrict__ slots, const float* __restrict__ ns) {
    int f = blockIdx.x * 256 + threadIdx.x;
    float4 s = F4(slots + (size_t)f * 4);
    float4 n = CF4(ns + (size_t)f * 4);
    s.x = 0.9f * s.x + 0.1f * n.x;
    s.y = 0.9f * s.y + 0.1f * n.y;
    s.z = 0.9f * s.z + 0.1f * n.z;
    s.w = 0.9f * s.w + 0.1f * n.w;
    F4(slots + (size_t)f * 4) = s;
}

// ---------------- q GEMM: q[m,o] = sum_k slots[m,k]*Wq[o,k] + bq[o] ----------------
// M=2048, N=512, K=512. Both operands k-contiguous. Tile 64x64, BK=32, 256 thr, 4x4/thr.
__global__ __launch_bounds__(256) void k_qgemm(const float* __restrict__ A,
                                               const float* __restrict__ Bm,
                                               const float* __restrict__ bq,
                                               float* __restrict__ Q) {
    __shared__ float As[64][36];   // 36*4=144B rows: 16B-aligned, bank-rotated
    __shared__ float Bs[64][36];
    int m0 = blockIdx.y * 64;
    int n0 = blockIdx.x * 64;
    int t = threadIdx.x;
    int ty = t >> 4, tx = t & 15;
    float c[4][4] = {};
    for (int k0 = 0; k0 < 512; k0 += 32) {
        int r = t >> 3;
        int kc = (t & 7) * 4;
        F4(&As[r][kc])      = CF4(A  + (size_t)(m0 + r)      * 512 + k0 + kc);
        F4(&As[r + 32][kc]) = CF4(A  + (size_t)(m0 + r + 32) * 512 + k0 + kc);
        F4(&Bs[r][kc])      = CF4(Bm + (size_t)(n0 + r)      * 512 + k0 + kc);
        F4(&Bs[r + 32][kc]) = CF4(Bm + (size_t)(n0 + r + 32) * 512 + k0 + kc);
        __syncthreads();
#pragma unroll
        for (int kq = 0; kq < 8; ++kq) {
            float4 av[4], bv[4];
#pragma unroll
            for (int ii = 0; ii < 4; ++ii) av[ii] = F4(&As[ty * 4 + ii][kq * 4]);
#pragma unroll
            for (int jj = 0; jj < 4; ++jj) bv[jj] = F4(&Bs[tx * 4 + jj][kq * 4]);
#pragma unroll
            for (int ii = 0; ii < 4; ++ii)
#pragma unroll
                for (int jj = 0; jj < 4; ++jj) {
                    c[ii][jj] = fmaf(av[ii].x, bv[jj].x, c[ii][jj]);
                    c[ii][jj] = fmaf(av[ii].y, bv[jj].y, c[ii][jj]);
                    c[ii][jj] = fmaf(av[ii].z, bv[jj].z, c[ii][jj]);
                    c[ii][jj] = fmaf(av[ii].w, bv[jj].w, c[ii][jj]);
                }
        }
        __syncthreads();
    }
    float4 bb = CF4(bq + n0 + tx * 4);
#pragma unroll
    for (int ii = 0; ii < 4; ++ii) {
        int m = m0 + ty * 4 + ii;
        float4 r;
        r.x = c[ii][0] + bb.x;
        r.y = c[ii][1] + bb.y;
        r.z = c[ii][2] + bb.z;
        r.w = c[ii][3] + bb.w;
        F4(Q + (size_t)m * 512 + n0 + tx * 4) = r;
    }
}

// ---------------- BN utils ----------------
__global__ void k_zero_stats(float* __restrict__ stats) {
    int i = blockIdx.x * 256 + threadIdx.x;
    if (i < 1088) stats[i] = 0.0f;   // sum1, sq1, sum2, sq2
}

// q (2048,512): per-column sum/sumsq. 64 blocks: 8 col-groups x 8 row-chunks.
__global__ __launch_bounds__(256) void k_bn1_stats(const float* __restrict__ Q,
                                                   float* __restrict__ stats) {
    int cg = blockIdx.x & 7, rc = blockIdx.x >> 3;
    int lc = threadIdx.x & 63;
    int col = cg * 64 + lc;
    int rsub = threadIdx.x >> 6;   // 0..3
    float s = 0.f, sq = 0.f;
    for (int k = 0; k < 64; ++k) {
        float v = Q[(size_t)(rc * 256 + rsub + 4 * k) * 512 + col];
        s += v;
        sq += v * v;
    }
    __shared__ float ls[4][64], lq[4][64];
    ls[rsub][lc] = s;
    lq[rsub][lc] = sq;
    __syncthreads();
    if (threadIdx.x < 64) {
        int tcol = threadIdx.x;
        float ts = ls[0][tcol] + ls[1][tcol] + ls[2][tcol] + ls[3][tcol];
        float tq = lq[0][tcol] + lq[1][tcol] + lq[2][tcol] + lq[3][tcol];
        atomicAdd(&stats[O_SUM1 + cg * 64 + tcol], ts);
        atomicAdd(&stats[O_SQ1 + cg * 64 + tcol], tq);
    }
}

__global__ void k_bn1_fin(float* __restrict__ stats, const float* __restrict__ g1,
                          const float* __restrict__ b1) {
    int c = threadIdx.x;   // 512
    float mean = stats[O_SUM1 + c] * (1.0f / 2048.0f);
    float var = stats[O_SQ1 + c] * (1.0f / 2048.0f) - mean * mean;
    float sc = rsqrtf(var + 1e-5f) * g1[c];
    stats[O_SC1 + c] = sc;
    stats[O_SH1 + c] = b1[c] - mean * sc;
}

// q = relu(q*scale + shift), elementwise
__global__ void k_bn1_apply(float* __restrict__ Q, const float* __restrict__ stats) {
    int f = blockIdx.x * 256 + threadIdx.x;   // 262144 float4
    int col4 = f & 127;
    float4 v = F4(Q + (size_t)f * 4);
    float4 sc = CF4(stats + O_SC1 + col4 * 4);
    float4 sh = CF4(stats + O_SH1 + col4 * 4);
    v.x = fmaxf(fmaf(v.x, sc.x, sh.x), 0.f);
    v.y = fmaxf(fmaf(v.y, sc.y, sh.y), 0.f);
    v.z = fmaxf(fmaf(v.z, sc.z, sh.z), 0.f);
    v.w = fmaxf(fmaf(v.w, sc.w, sh.w), 0.f);
    F4(Q + (size_t)f * 4) = v;
}

// ---------------- GEMM1: attn[b,i,j] = sum_d q[b*32+i,d] * x[b,d,j] ----------------
// Per block: one batch, 32i x 128j tile, BK=32. 256 thr (8 x 32), 4x4/thr.
__global__ __launch_bounds__(256) void k_gemm1(const float* __restrict__ Q,
                                               const float* __restrict__ X,
                                               float* __restrict__ attn) {
    __shared__ float qs[32][36];
    __shared__ float xs[32][128];
    int b = blockIdx.y;
    int j0 = blockIdx.x * 128;
    int t = threadIdx.x;
    int ty = t >> 5;   // 0..7  -> i quad
    int tx = t & 31;   // 0..31 -> j quad
    float c[4][4] = {};
    const float* qb = Q + (size_t)b * 32 * 512;
    const float* xb = X + (size_t)b * 512 * 4096;
    for (int k0 = 0; k0 < 512; k0 += 32) {
        {
            int r = t >> 3;
            int kc = (t & 7) * 4;
            F4(&qs[r][kc]) = CF4(qb + (size_t)r * 512 + k0 + kc);
        }
#pragma unroll
        for (int rr = 0; rr < 4; ++rr) {
            int r = (t >> 5) + 8 * rr;
            F4(&xs[r][tx * 4]) = CF4(xb + (size_t)(k0 + r) * 4096 + j0 + tx * 4);
        }
        __syncthreads();
#pragma unroll
        for (int kq = 0; kq < 8; ++kq) {
            float4 av[4];
#pragma unroll
            for (int ii = 0; ii < 4; ++ii) av[ii] = F4(&qs[ty * 4 + ii][kq * 4]);
#pragma unroll
            for (int kk = 0; kk < 4; ++kk) {
                float4 bv = F4(&xs[kq * 4 + kk][tx * 4]);
#pragma unroll
                for (int ii = 0; ii < 4; ++ii) {
                    float a = (kk == 0) ? av[ii].x : (kk == 1) ? av[ii].y
                              : (kk == 2) ? av[ii].z : av[ii].w;
                    c[ii][0] = fmaf(a, bv.x, c[ii][0]);
                    c[ii][1] = fmaf(a, bv.y, c[ii][1]);
                    c[ii][2] = fmaf(a, bv.z, c[ii][2]);
                    c[ii][3] = fmaf(a, bv.w, c[ii][3]);
                }
            }
        }
        __syncthreads();
    }
#pragma unroll
    for (int ii = 0; ii < 4; ++ii) {
        float4 r;
        r.x = c[ii][0]; r.y = c[ii][1]; r.z = c[ii][2]; r.w = c[ii][3];
        F4(attn + (size_t)(b * 32 + ty * 4 + ii) * 4096 + j0 + tx * 4) = r;
    }
}

// ---------------- BN2 over attn: per-channel i (reduce b,hw) ----------------
__global__ __launch_bounds__(256) void k_bn2_stats(const float* __restrict__ attn,
                                                   float* __restrict__ stats) {
    int i = blockIdx.x, b = blockIdx.y;
    const float* p = attn + (size_t)(b * 32 + i) * 4096;
    int t = threadIdx.x;
    float s = 0.f, sq = 0.f;
#pragma unroll
    for (int c = 0; c < 4; ++c) {
        float4 v = CF4(p + (size_t)(t + 256 * c) * 4);
        s += v.x + v.y + v.z + v.w;
        sq += v.x * v.x + v.y * v.y + v.z * v.z + v.w * v.w;
    }
    __shared__ float rs[256], rq[256];
    rs[t] = s; rq[t] = sq;
    __syncthreads();
    for (int off = 128; off > 0; off >>= 1) {
        if (t < off) { rs[t] += rs[t + off]; rq[t] += rq[t + off]; }
        __syncthreads();
    }
    if (t == 0) {
        atomicAdd(&stats[O_SUM2 + i], rs[0]);
        atomicAdd(&stats[O_SQ2 + i], rq[0]);
    }
}

__global__ void k_bn2_fin(float* __restrict__ stats, const float* __restrict__ g2,
                          const float* __restrict__ b2) {
    int i = threadIdx.x;   // 32
    const float inv = 1.0f / 262144.0f;
    float mean = stats[O_SUM2 + i] * inv;
    float var = stats[O_SQ2 + i] * inv - mean * mean;
    float sc = rsqrtf(var + 1e-5f) * g2[i];
    stats[O_SC2 + i] = sc;
    stats[O_SH2 + i] = b2[i] - mean * sc;
}

// attn = relu(attn*sc + sh) in-place; rowsum[b*32+i] = sum_j attn
__global__ __launch_bounds__(256) void k_bn2_apply(float* __restrict__ attn,
                                                   float* __restrict__ stats) {
    int i = blockIdx.x, b = blockIdx.y;
    float* p = attn + (size_t)(b * 32 + i) * 4096;
    float sc = stats[O_SC2 + i], sh = stats[O_SH2 + i];
    int t = threadIdx.x;
    float s = 0.f;
#pragma unroll
    for (int c = 0; c < 4; ++c) {
        float4 v = F4(p + (size_t)(t + 256 * c) * 4);
        v.x = fmaxf(fmaf(v.x, sc, sh), 0.f);
        v.y = fmaxf(fmaf(v.y, sc, sh), 0.f);
        v.z = fmaxf(fmaf(v.z, sc, sh), 0.f);
        v.w = fmaxf(fmaf(v.w, sc, sh), 0.f);
        s += v.x + v.y + v.z + v.w;
        F4(p + (size_t)(t + 256 * c) * 4) = v;
    }
    __shared__ float rs[256];
    rs[t] = s;
    __syncthreads();
    for (int off = 128; off > 0; off >>= 1) {
        if (t < off) rs[t] += rs[t + off];
        __syncthreads();
    }
    if (t == 0) stats[O_RS + b * 32 + i] = rs[0];
}

// ---------------- GEMM2: out[b*32+i,d] = (sum_j attn[b,i,j]*x[b,d,j]) / (rowsum + eps) ----------------
// Per block: one batch, 32i x 64d tile, BK=64 over j. 128 thr (8 x 16), 4x4/thr.
__global__ __launch_bounds__(128) void k_gemm2(const float* __restrict__ attn,
                                               const float* __restrict__ X,
                                               const float* __restrict__ stats,
                                               float* __restrict__ out) {
    __shared__ float as_[32][68];   // 68*4=272B rows: 16B aligned
    __shared__ float bs_[64][68];
    int b = blockIdx.y;
    int d0 = blockIdx.x * 64;
    int t = threadIdx.x;
    int ty = t >> 4;   // 0..7  -> i quad
    int tx = t & 15;   // 0..15 -> d quad
    float c[4][4] = {};
    const float* ab = attn + (size_t)b * 32 * 4096;
    const float* xb = X + ((size_t)b * 512 + d0) * 4096;
    for (int jk = 0; jk < 4096; jk += 64) {
#pragma unroll
        for (int ci = 0; ci < 4; ++ci) {
            int f = t + 128 * ci;             // 0..511
            int r = f >> 4, c4 = (f & 15) * 4;
            F4(&as_[r][c4]) = CF4(ab + (size_t)r * 4096 + jk + c4);
        }
#pragma unroll
        for (int ci = 0; ci < 8; ++ci) {
            int f = t + 128 * ci;             // 0..1023
            int r = f >> 4, c4 = (f & 15) * 4;
            F4(&bs_[r][c4]) = CF4(xb + (size_t)r * 4096 + jk + c4);
        }
        __syncthreads();
#pragma unroll
        for (int jq = 0; jq < 16; ++jq) {
            float4 av[4], bv[4];
#pragma unroll
            for (int ii = 0; ii < 4; ++ii) av[ii] = F4(&as_[ty * 4 + ii][jq * 4]);
#pragma unroll
            for (int dd = 0; dd < 4; ++dd) bv[dd] = F4(&bs_[tx * 4 + dd][jq * 4]);
#pragma unroll
            for (int ii = 0; ii < 4; ++ii)
#pragma unroll
                for (int dd = 0; dd < 4; ++dd) {
                    c[ii][dd] = fmaf(av[ii].x, bv[dd].x, c[ii][dd]);
                    c[ii][dd] = fmaf(av[ii].y, bv[dd].y, c[ii][dd]);
                    c[ii][dd] = fmaf(av[ii].z, bv[dd].z, c[ii][dd]);
                    c[ii][dd] = fmaf(av[ii].w, bv[dd].w, c[ii][dd]);
                }
        }
        __syncthreads();
    }
#pragma unroll
    for (int ii = 0; ii < 4; ++ii) {
        int row = b * 32 + ty * 4 + ii;
        float inv = 1.0f / (stats[O_RS + row] + 1e-12f);
        float4 r;
        r.x = c[ii][0] * inv; r.y = c[ii][1] * inv;
        r.z = c[ii][2] * inv; r.w = c[ii][3] * inv;
        F4(out + (size_t)row * 512 + d0 + tx * 4) = r;
    }
}

extern "C" void kernel_launch(void* const* d_in, const int* in_sizes, int n_in,
                              void* d_out, int out_size, void* d_ws, size_t ws_size,
                              hipStream_t stream) {
    const float* x    = (const float*)d_in[0];
    const float* meta = (const float*)d_in[1];
    const float* Wq   = (const float*)d_in[2];
    const float* bq   = (const float*)d_in[3];
    const float* g1   = (const float*)d_in[4];
    const float* b1   = (const float*)d_in[5];
    const float* g2   = (const float*)d_in[6];
    const float* b2   = (const float*)d_in[7];
    float* out = (float*)d_out;

    float* ws = (float*)d_ws;
    float* slots = ws;                 // 1048576 floats (4 MB)
    float* q     = ws + 1048576;       // 1048576 floats (4 MB)
    float* attn  = ws + 2097152;       // 8388608 floats (32 MB)
    float* stats = ws + 10485760;      // 4224 floats

    k_init_slots<<<1024, 256, 0, stream>>>(meta, slots);
    for (int it = 0; it < 3; ++it) {
        if (it > 0) k_blend<<<1024, 256, 0, stream>>>(slots, out);
        k_qgemm<<<dim3(8, 32), 256, 0, stream>>>(slots, Wq, bq, q);
        k_zero_stats<<<5, 256, 0, stream>>>(stats);
        k_bn1_stats<<<64, 256, 0, stream>>>(q, stats);
        k_bn1_fin<<<1, 512, 0, stream>>>(stats, g1, b1);
        k_bn1_apply<<<1024, 256, 0, stream>>>(q, stats);
        k_gemm1<<<dim3(32, 64), 256, 0, stream>>>(q, x, attn);
        k_bn2_stats<<<dim3(32, 64), 256, 0, stream>>>(attn, stats);
        k_bn2_fin<<<1, 32, 0, stream>>>(stats, g2, b2);
        k_bn2_apply<<<dim3(32, 64), 256, 0, stream>>>(attn, stats);
        k_gemm2<<<dim3(8, 64), 128, 0, stream>>>(attn, x, stats, out);
    }
}

// Round 2
// 2121.039 us; speedup vs baseline: 1.4703x; 1.4703x over previous
//
#include <hip/hip_runtime.h>

// b=64, c=d=512, hw=4096, n=32, M=b*n=2048, 3 slot-attention iterations.
// x(64,512,4096) fp32, j-contiguous. All GEMMs restructured conflict-free:
// LDS K-major, A broadcast-read, B lane-consecutive float4 read, 8x8/thread.

#define F4(p)  (*reinterpret_cast<float4*>(p))
#define CF4(p) (*reinterpret_cast<const float4*>(p))

// stats buffer float offsets
#define O_SUM1 0
#define O_SQ1  512
#define O_SUM2 1024
#define O_SQ2  1056
#define O_SC1  1088
#define O_SH1  1600
#define O_SC2  2112
#define O_SH2  2144
#define O_RS   2176   // rowsum[2048]

typedef __attribute__((address_space(1))) const void gvoid_t;
typedef __attribute__((address_space(3))) void lvoid_t;
__device__ __forceinline__ void gload_lds16(const float* g, float* l) {
    // async global->LDS, 16B/lane; LDS dest = wave-uniform base + lane*16
    __builtin_amdgcn_global_load_lds((gvoid_t*)g, (lvoid_t*)l, 16, 0, 0);
}

// ---------------- init / blend / zero ----------------
__global__ void k_init_slots(const float* __restrict__ meta, float* __restrict__ slots) {
    int f = blockIdx.x * 256 + threadIdx.x;      // float4 index, 262144
    int m = f >> 7;
    int d4 = f & 127;
    F4(slots + (size_t)f * 4) = CF4(meta + ((size_t)((m & 31) << 7) + d4) * 4);
}

__global__ void k_blend(float* __restrict__ slots, const float* __restrict__ ns) {
    int f = blockIdx.x * 256 + threadIdx.x;
    float4 s = F4(slots + (size_t)f * 4);
    float4 n = CF4(ns + (size_t)f * 4);
    s.x = 0.9f * s.x + 0.1f * n.x;
    s.y = 0.9f * s.y + 0.1f * n.y;
    s.z = 0.9f * s.z + 0.1f * n.z;
    s.w = 0.9f * s.w + 0.1f * n.w;
    F4(slots + (size_t)f * 4) = s;
}

// q[m][n] = bq[n]  (bias folded into init; qgemm atomicAdds partial sums)
__global__ void k_qinit(const float* __restrict__ bq, float* __restrict__ Q) {
    int f = blockIdx.x * 256 + threadIdx.x;   // 262144 float4
    F4(Q + (size_t)f * 4) = CF4(bq + (size_t)(f & 127) * 4);
}

__global__ void k_zero_out(float* __restrict__ out) {
    int f = blockIdx.x * 256 + threadIdx.x;   // 262144 float4
    float4 z = {0.f, 0.f, 0.f, 0.f};
    F4(out + (size_t)f * 4) = z;
}

// ---------------- qgemm: q[m,o] += sum_k slots[m,k]*Wq[o,k], K-split x4 ----------------
// grid (64 m-tiles of 32, 4 k-splits), 256 thr, 8x8/thread, block covers 32m x 512n.
__global__ __launch_bounds__(256) void k_qgemm(const float* __restrict__ S,
                                               const float* __restrict__ Wq,
                                               float* __restrict__ Q) {
    __shared__ __align__(16) float asT[32][36];    // [k][m]
    __shared__ __align__(16) float bsT[32][516];   // [k][n]
    const int m0 = blockIdx.x * 32;
    const int kbase = blockIdx.y * 128;
    const int t = threadIdx.x;
    const int ty = t >> 6, tx = t & 63;
    float c[8][8] = {};
    for (int ch = 0; ch < 4; ++ch) {
        int k0 = kbase + ch * 32;
        {   // slots tile 32m x 32k -> asT[k][m]
            int m = t >> 3, kq = t & 7;
            float4 v = CF4(S + (size_t)(m0 + m) * 512 + k0 + kq * 4);
            asT[kq * 4 + 0][m] = v.x; asT[kq * 4 + 1][m] = v.y;
            asT[kq * 4 + 2][m] = v.z; asT[kq * 4 + 3][m] = v.w;
        }
#pragma unroll
        for (int cc = 0; cc < 16; ++cc) {   // Wq tile 512n x 32k -> bsT[k][n]
            int lin = t + 256 * cc;
            int n = lin >> 3, kq = lin & 7;
            float4 v = CF4(Wq + (size_t)n * 512 + k0 + kq * 4);
            bsT[kq * 4 + 0][n] = v.x; bsT[kq * 4 + 1][n] = v.y;
            bsT[kq * 4 + 2][n] = v.z; bsT[kq * 4 + 3][n] = v.w;
        }
        __syncthreads();
#pragma unroll 8
        for (int k = 0; k < 32; ++k) {
            float4 a0 = F4(&asT[k][ty * 8]);
            float4 a1 = F4(&asT[k][ty * 8 + 4]);
            float4 b0 = F4(&bsT[k][tx * 4]);
            float4 b1 = F4(&bsT[k][256 + tx * 4]);
            float av[8] = {a0.x, a0.y, a0.z, a0.w, a1.x, a1.y, a1.z, a1.w};
            float bv[8] = {b0.x, b0.y, b0.z, b0.w, b1.x, b1.y, b1.z, b1.w};
#pragma unroll
            for (int ii = 0; ii < 8; ++ii)
#pragma unroll
                for (int jj = 0; jj < 8; ++jj)
                    c[ii][jj] = fmaf(av[ii], bv[jj], c[ii][jj]);
        }
        __syncthreads();
    }
#pragma unroll
    for (int ii = 0; ii < 8; ++ii) {
        float* dst = Q + (size_t)(m0 + ty * 8 + ii) * 512;
#pragma unroll
        for (int q = 0; q < 4; ++q) atomicAdd(dst + tx * 4 + q, c[ii][q]);
#pragma unroll
        for (int q = 0; q < 4; ++q) atomicAdd(dst + 256 + tx * 4 + q, c[ii][4 + q]);
    }
}

// ---------------- BN1 ----------------
__global__ void k_zero_stats(float* __restrict__ stats) {
    int i = blockIdx.x * 256 + threadIdx.x;
    if (i < 1088) stats[i] = 0.0f;
}

__global__ __launch_bounds__(256) void k_bn1_stats(const float* __restrict__ Q,
                                                   float* __restrict__ stats) {
    int cg = blockIdx.x & 7, rc = blockIdx.x >> 3;
    int lc = threadIdx.x & 63;
    int col = cg * 64 + lc;
    int rsub = threadIdx.x >> 6;
    float s = 0.f, sq = 0.f;
    for (int k = 0; k < 64; ++k) {
        float v = Q[(size_t)(rc * 256 + rsub + 4 * k) * 512 + col];
        s += v;
        sq += v * v;
    }
    __shared__ float ls[4][64], lq[4][64];
    ls[rsub][lc] = s;
    lq[rsub][lc] = sq;
    __syncthreads();
    if (threadIdx.x < 64) {
        int tcol = threadIdx.x;
        float ts = ls[0][tcol] + ls[1][tcol] + ls[2][tcol] + ls[3][tcol];
        float tq = lq[0][tcol] + lq[1][tcol] + lq[2][tcol] + lq[3][tcol];
        atomicAdd(&stats[O_SUM1 + cg * 64 + tcol], ts);
        atomicAdd(&stats[O_SQ1 + cg * 64 + tcol], tq);
    }
}

__global__ void k_bn1_fin(float* __restrict__ stats, const float* __restrict__ g1,
                          const float* __restrict__ b1) {
    int c = threadIdx.x;
    float mean = stats[O_SUM1 + c] * (1.0f / 2048.0f);
    float var = stats[O_SQ1 + c] * (1.0f / 2048.0f) - mean * mean;
    float sc = rsqrtf(var + 1e-5f) * g1[c];
    stats[O_SC1 + c] = sc;
    stats[O_SH1 + c] = b1[c] - mean * sc;
}

__global__ void k_bn1_apply(float* __restrict__ Q, const float* __restrict__ stats) {
    int f = blockIdx.x * 256 + threadIdx.x;
    int col4 = f & 127;
    float4 v = F4(Q + (size_t)f * 4);
    float4 sc = CF4(stats + O_SC1 + col4 * 4);
    float4 sh = CF4(stats + O_SH1 + col4 * 4);
    v.x = fmaxf(fmaf(v.x, sc.x, sh.x), 0.f);
    v.y = fmaxf(fmaf(v.y, sc.y, sh.y), 0.f);
    v.z = fmaxf(fmaf(v.z, sc.z, sh.z), 0.f);
    v.w = fmaxf(fmaf(v.w, sc.w, sh.w), 0.f);
    F4(Q + (size_t)f * 4) = v;
}

// ---------------- GEMM1: attn[b,i,j] = sum_k q[b*32+i,k]*x[b,k,j] ----------------
// grid (8 j-tiles of 512, 64 b), 256 thr. Per-thread 8i x (4j + 4j@+256).
__global__ __launch_bounds__(256) void k_gemm1(const float* __restrict__ Q,
                                               const float* __restrict__ X,
                                               float* __restrict__ attn) {
    __shared__ __align__(16) float qsT[32][36];   // [k][i]
    __shared__ __align__(16) float xs[32][512];   // [k][j] direct layout
    const int b = blockIdx.y;
    const int j0 = blockIdx.x * 512;
    const int t = threadIdx.x;
    const int w = t >> 6, l = t & 63;
    const int ty = w, tx = l;
    const float* qb = Q + (size_t)b * 32 * 512;
    const float* xb = X + (size_t)b * 512 * 4096 + j0;
    float c[8][8] = {};
    for (int k0 = 0; k0 < 512; k0 += 32) {
        {   // q tile 32i x 32k -> qsT[k][i]
            int i = t >> 3, kq = t & 7;
            float4 v = CF4(qb + (size_t)i * 512 + k0 + kq * 4);
            qsT[kq * 4 + 0][i] = v.x; qsT[kq * 4 + 1][i] = v.y;
            qsT[kq * 4 + 2][i] = v.z; qsT[kq * 4 + 3][i] = v.w;
        }
        // x tile 32k x 512j: async 1KB chunks, wave-uniform LDS dest
#pragma unroll
        for (int cc = 0; cc < 16; ++cc) {
            int chunk = w * 16 + cc;          // 0..63
            int row = chunk >> 1, half = chunk & 1;
            const float* src = xb + (size_t)(k0 + row) * 4096 + half * 256 + l * 4;
            gload_lds16(src, &xs[row][half * 256]);
        }
        __syncthreads();
#pragma unroll 8
        for (int k = 0; k < 32; ++k) {
            float4 a0 = F4(&qsT[k][ty * 8]);
            float4 a1 = F4(&qsT[k][ty * 8 + 4]);
            float4 b0 = F4(&xs[k][tx * 4]);
            float4 b1 = F4(&xs[k][256 + tx * 4]);
            float av[8] = {a0.x, a0.y, a0.z, a0.w, a1.x, a1.y, a1.z, a1.w};
            float bv[8] = {b0.x, b0.y, b0.z, b0.w, b1.x, b1.y, b1.z, b1.w};
#pragma unroll
            for (int ii = 0; ii < 8; ++ii)
#pragma unroll
                for (int jj = 0; jj < 8; ++jj)
                    c[ii][jj] = fmaf(av[ii], bv[jj], c[ii][jj]);
        }
        __syncthreads();
    }
#pragma unroll
    for (int ii = 0; ii < 8; ++ii) {
        float* dst = attn + (size_t)(b * 32 + ty * 8 + ii) * 4096 + j0;
        float4 r0 = {c[ii][0], c[ii][1], c[ii][2], c[ii][3]};
        float4 r1 = {c[ii][4], c[ii][5], c[ii][6], c[ii][7]};
        F4(dst + tx * 4) = r0;
        F4(dst + 256 + tx * 4) = r1;
    }
}

// ---------------- BN2 ----------------
__global__ __launch_bounds__(256) void k_bn2_stats(const float* __restrict__ attn,
                                                   float* __restrict__ stats) {
    int i = blockIdx.x, b = blockIdx.y;
    const float* p = attn + (size_t)(b * 32 + i) * 4096;
    int t = threadIdx.x;
    float s = 0.f, sq = 0.f;
#pragma unroll
    for (int c = 0; c < 4; ++c) {
        float4 v = CF4(p + (size_t)(t + 256 * c) * 4);
        s += v.x + v.y + v.z + v.w;
        sq += v.x * v.x + v.y * v.y + v.z * v.z + v.w * v.w;
    }
    __shared__ float rs[256], rq[256];
    rs[t] = s; rq[t] = sq;
    __syncthreads();
    for (int off = 128; off > 0; off >>= 1) {
        if (t < off) { rs[t] += rs[t + off]; rq[t] += rq[t + off]; }
        __syncthreads();
    }
    if (t == 0) {
        atomicAdd(&stats[O_SUM2 + i], rs[0]);
        atomicAdd(&stats[O_SQ2 + i], rq[0]);
    }
}

__global__ void k_bn2_fin(float* __restrict__ stats, const float* __restrict__ g2,
                          const float* __restrict__ b2) {
    int i = threadIdx.x;
    const float inv = 1.0f / 262144.0f;
    float mean = stats[O_SUM2 + i] * inv;
    float var = stats[O_SQ2 + i] * inv - mean * mean;
    float sc = rsqrtf(var + 1e-5f) * g2[i];
    stats[O_SC2 + i] = sc;
    stats[O_SH2 + i] = b2[i] - mean * sc;
}

__global__ __launch_bounds__(256) void k_bn2_apply(float* __restrict__ attn,
                                                   float* __restrict__ stats) {
    int i = blockIdx.x, b = blockIdx.y;
    float* p = attn + (size_t)(b * 32 + i) * 4096;
    float sc = stats[O_SC2 + i], sh = stats[O_SH2 + i];
    int t = threadIdx.x;
    float s = 0.f;
#pragma unroll
    for (int c = 0; c < 4; ++c) {
        float4 v = F4(p + (size_t)(t + 256 * c) * 4);
        v.x = fmaxf(fmaf(v.x, sc, sh), 0.f);
        v.y = fmaxf(fmaf(v.y, sc, sh), 0.f);
        v.z = fmaxf(fmaf(v.z, sc, sh), 0.f);
        v.w = fmaxf(fmaf(v.w, sc, sh), 0.f);
        s += v.x + v.y + v.z + v.w;
        F4(p + (size_t)(t + 256 * c) * 4) = v;
    }
    __shared__ float rs[256];
    rs[t] = s;
    __syncthreads();
    for (int off = 128; off > 0; off >>= 1) {
        if (t < off) rs[t] += rs[t + off];
        __syncthreads();
    }
    if (t == 0) stats[O_RS + b * 32 + i] = rs[0];
}

// ---------------- GEMM2: out[b*32+i,d] += sum_{j in split} attn[b,i,j]*x[b,d,j]*inv_rs ----------------
// grid (8 j-splits of 512, 64 b), 256 thr. Block covers 32i x 512d, j-chunks of 32.
__global__ __launch_bounds__(256) void k_gemm2(const float* __restrict__ attn,
                                               const float* __restrict__ X,
                                               const float* __restrict__ stats,
                                               float* __restrict__ out) {
    __shared__ __align__(16) float asT[32][36];    // [j][i]
    __shared__ __align__(16) float xsT[32][516];   // [j][d]
    const int b = blockIdx.y;
    const int jbase0 = blockIdx.x * 512;
    const int t = threadIdx.x;
    const int ty = t >> 6, tx = t & 63;
    const float* ab = attn + (size_t)b * 32 * 4096 + jbase0;
    const float* xb = X + (size_t)b * 512 * 4096 + jbase0;
    float c[8][8] = {};
    for (int ch = 0; ch < 16; ++ch) {
        int jb = ch * 32;
        {   // attn tile 32i x 32j -> asT[j][i]
            int i = t >> 3, jq = t & 7;
            float4 v = CF4(ab + (size_t)i * 4096 + jb + jq * 4);
            asT[jq * 4 + 0][i] = v.x; asT[jq * 4 + 1][i] = v.y;
            asT[jq * 4 + 2][i] = v.z; asT[jq * 4 + 3][i] = v.w;
        }
#pragma unroll
        for (int cc = 0; cc < 16; ++cc) {   // x tile 512d x 32j -> xsT[j][d]
            int lin = t + 256 * cc;         // 0..4095
            int d = lin >> 3, jq = lin & 7;
            float4 v = CF4(xb + (size_t)d * 4096 + jb + jq * 4);
            xsT[jq * 4 + 0][d] = v.x; xsT[jq * 4 + 1][d] = v.y;
            xsT[jq * 4 + 2][d] = v.z; xsT[jq * 4 + 3][d] = v.w;
        }
        __syncthreads();
#pragma unroll 8
        for (int k = 0; k < 32; ++k) {
            float4 a0 = F4(&asT[k][ty * 8]);
            float4 a1 = F4(&asT[k][ty * 8 + 4]);
            float4 b0 = F4(&xsT[k][tx * 4]);
            float4 b1 = F4(&xsT[k][256 + tx * 4]);
            float av[8] = {a0.x, a0.y, a0.z, a0.w, a1.x, a1.y, a1.z, a1.w};
            float bv[8] = {b0.x, b0.y, b0.z, b0.w, b1.x, b1.y, b1.z, b1.w};
#pragma unroll
            for (int ii = 0; ii < 8; ++ii)
#pragma unroll
                for (int jj = 0; jj < 8; ++jj)
                    c[ii][jj] = fmaf(av[ii], bv[jj], c[ii][jj]);
        }
        __syncthreads();
    }
#pragma unroll
    for (int ii = 0; ii < 8; ++ii) {
        int row = b * 32 + ty * 8 + ii;
        float inv = 1.0f / (stats[O_RS + row] + 1e-12f);
        float* dst = out + (size_t)row * 512;
#pragma unroll
        for (int q = 0; q < 4; ++q) atomicAdd(dst + tx * 4 + q, c[ii][q] * inv);
#pragma unroll
        for (int q = 0; q < 4; ++q) atomicAdd(dst + 256 + tx * 4 + q, c[ii][4 + q] * inv);
    }
}

extern "C" void kernel_launch(void* const* d_in, const int* in_sizes, int n_in,
                              void* d_out, int out_size, void* d_ws, size_t ws_size,
                              hipStream_t stream) {
    const float* x    = (const float*)d_in[0];
    const float* meta = (const float*)d_in[1];
    const float* Wq   = (const float*)d_in[2];
    const float* bq   = (const float*)d_in[3];
    const float* g1   = (const float*)d_in[4];
    const float* b1   = (const float*)d_in[5];
    const float* g2   = (const float*)d_in[6];
    const float* b2   = (const float*)d_in[7];
    float* out = (float*)d_out;

    float* ws = (float*)d_ws;
    float* slots = ws;                 // 1048576 floats
    float* q     = ws + 1048576;       // 1048576 floats
    float* attn  = ws + 2097152;       // 8388608 floats
    float* stats = ws + 10485760;      // 4224 floats

    k_init_slots<<<1024, 256, 0, stream>>>(meta, slots);
    for (int it = 0; it < 3; ++it) {
        if (it > 0) k_blend<<<1024, 256, 0, stream>>>(slots, out);
        k_qinit<<<1024, 256, 0, stream>>>(bq, q);
        k_qgemm<<<dim3(64, 4), 256, 0, stream>>>(slots, Wq, q);
        k_zero_stats<<<5, 256, 0, stream>>>(stats);
        k_bn1_stats<<<64, 256, 0, stream>>>(q, stats);
        k_bn1_fin<<<1, 512, 0, stream>>>(stats, g1, b1);
        k_bn1_apply<<<1024, 256, 0, stream>>>(q, stats);
        k_gemm1<<<dim3(8, 64), 256, 0, stream>>>(q, x, attn);
        k_bn2_stats<<<dim3(32, 64), 256, 0, stream>>>(attn, stats);
        k_bn2_fin<<<1, 32, 0, stream>>>(stats, g2, b2);
        k_bn2_apply<<<dim3(32, 64), 256, 0, stream>>>(attn, stats);
        k_zero_out<<<1024, 256, 0, stream>>>(out);
        k_gemm2<<<dim3(8, 64), 256, 0, stream>>>(attn, x, stats, out);
    }
}